// Round 16
// baseline (553.755 us; speedup 1.0000x reference)
//
#include <hip/hip_runtime.h>

typedef unsigned short u16;
typedef unsigned int u32;
typedef __attribute__((ext_vector_type(8))) short short8;
typedef __attribute__((ext_vector_type(4))) float f32x4;
typedef __attribute__((ext_vector_type(16))) float f32x16;

// ---------- helpers ----------
__device__ __forceinline__ u16 f2bf(float f) {
  union { float f; unsigned int u; } v; v.f = f;
  unsigned int r = v.u + 0x7FFFu + ((v.u >> 16) & 1u);  // RNE
  return (u16)(r >> 16);
}
__device__ __forceinline__ float bf2f(u16 b) {
  union { unsigned int u; float f; } v; v.u = ((unsigned int)b) << 16;
  return v.f;
}

__device__ __forceinline__ void gload_lds16(const void* g, void* l) {
  __builtin_amdgcn_global_load_lds((const __attribute__((address_space(1))) void*)g,
                                   (__attribute__((address_space(3))) void*)l, 16, 0, 0);
}

__device__ __forceinline__ u32 cvtpk_bf16(float lo, float hi) {
  u32 r;
  asm("v_cvt_pk_bf16_f32 %0, %1, %2" : "=v"(r) : "v"(lo), "v"(hi));
  return r;
}

__device__ __forceinline__ void plswap32(u32& a, u32& b) {
#if __has_builtin(__builtin_amdgcn_permlane32_swap)
  auto r = __builtin_amdgcn_permlane32_swap((int)a, (int)b, false, false);
  a = (u32)r[0]; b = (u32)r[1];
#else
  asm volatile("v_permlane32_swap_b32 %0, %1" : "+v"(a), "+v"(b));
#endif
}

__device__ __forceinline__ void plswapf(float& a, float& b) {
  union { float f; u32 u; } x, y; x.f = a; y.f = b;
  plswap32(x.u, y.u);
  a = x.f; b = y.f;
}

template <int N>
__device__ __forceinline__ void wait_vm() {
  if constexpr (N == 0) asm volatile("s_waitcnt vmcnt(0)" ::: "memory");
  else if constexpr (N == 3) asm volatile("s_waitcnt vmcnt(3)" ::: "memory");
  else if constexpr (N == 4) asm volatile("s_waitcnt vmcnt(4)" ::: "memory");
  else if constexpr (N == 6) asm volatile("s_waitcnt vmcnt(6)" ::: "memory");
  else if constexpr (N == 8) asm volatile("s_waitcnt vmcnt(8)" ::: "memory");
}
// counted lgkm gate; n is compile-time constant after unrolling
__device__ __forceinline__ void lgkm_gate(int n) {
  switch (n) {
    case 0: asm volatile("s_waitcnt lgkmcnt(0)" ::: "memory"); break;
    case 1: asm volatile("s_waitcnt lgkmcnt(1)" ::: "memory"); break;
    case 2: asm volatile("s_waitcnt lgkmcnt(2)" ::: "memory"); break;
    case 3: asm volatile("s_waitcnt lgkmcnt(3)" ::: "memory"); break;
    case 4: asm volatile("s_waitcnt lgkmcnt(4)" ::: "memory"); break;
    case 5: asm volatile("s_waitcnt lgkmcnt(5)" ::: "memory"); break;
    case 6: asm volatile("s_waitcnt lgkmcnt(6)" ::: "memory"); break;
    default: asm volatile("s_waitcnt lgkmcnt(7)" ::: "memory"); break;
  }
}
#define SBAR() __builtin_amdgcn_sched_barrier(0)

// order-pinned LDS read (asm volatile => issue order preserved for counted gates)
__device__ __forceinline__ u32 lds_off(const void* p) {
  return (u32)(size_t)(const __attribute__((address_space(3))) void*)p;
}
__device__ __forceinline__ short8 ds_read128(u32 off) {
  short8 d;
  asm volatile("ds_read_b128 %0, %1" : "=v"(d) : "v"(off));
  return d;
}

// ---------- f32 -> bf16 convert ----------
__global__ __launch_bounds__(256) void cvt_f32_bf16(const float* __restrict__ in,
                                                    u16* __restrict__ out, long n) {
  long i = ((long)blockIdx.x * 256 + threadIdx.x) * 4;
  if (i + 3 < n) {
    float4 v = *(const float4*)(in + i);
    unsigned long long p = (unsigned long long)f2bf(v.x) |
                           ((unsigned long long)f2bf(v.y) << 16) |
                           ((unsigned long long)f2bf(v.z) << 32) |
                           ((unsigned long long)f2bf(v.w) << 48);
    *(unsigned long long*)(out + i) = p;
  }
}

// ---------- weight transpose+convert: W[K,N] f32 -> WT[N,K] bf16 ----------
__global__ __launch_bounds__(256) void wtrans(const float* __restrict__ W,
                                              u16* __restrict__ WT, int K, int N) {
  __shared__ float t[32][33];
  int n0 = blockIdx.x * 32, k0 = blockIdx.y * 32;
  int tx = threadIdx.x, ty = threadIdx.y;
#pragma unroll
  for (int r = 0; r < 4; r++)
    t[ty + r * 8][tx] = W[(long)(k0 + ty + r * 8) * N + n0 + tx];
  __syncthreads();
#pragma unroll
  for (int r = 0; r < 4; r++)
    WT[(long)(n0 + ty + r * 8) * K + k0 + tx] = f2bf(t[tx][ty + r * 8]);
}

// ---------- V transpose: [b, n, head_off + h*64 + d] -> [bh][d][n] ----------
__global__ __launch_bounds__(256) void vtrans(const u16* __restrict__ src,
                                              u16* __restrict__ dst,
                                              int rows, int rstride, int head_off, int H) {
  __shared__ u16 t[64][65];
  int bh = blockIdx.y;
  int b = bh / H, h = bh % H;
  long n0 = (long)blockIdx.x * 64;
  const u16* s = src + (long)b * rows * rstride + head_off + h * 64;
  int q = threadIdx.x >> 6, ln = threadIdx.x & 63;
#pragma unroll
  for (int r = 0; r < 16; r++) {
    int nl = q * 16 + r;
    t[nl][ln] = s[(n0 + nl) * (long)rstride + ln];
  }
  __syncthreads();
  u16* d = dst + (long)bh * 64 * rows;
#pragma unroll
  for (int r = 0; r < 16; r++) {
    int dd = q * 16 + r;
    d[(long)dd * rows + n0 + ln] = t[ln][dd];
  }
}

// ---------- gemm10: gemm4 schedule with 32x32x16 MFMA geometry ----------
// Wave tile (BM/WM) x (BN/WN) as MT x NT tiles of 32x32; per K-half (32) two
// K-chunks of 16. A-frag: m=lane&31, k=8*(lane>>5)+e (layout validated in attn).
// C: col=lane&31, row=(reg&3)+8*(reg>>2)+4*(lane>>5). Same LDS layout/swizzle,
// staging, vmcnt ledger as gemm4; 2 lgkm gates per half, pinned read order.
template <int BN, int WM, int GELU>
__global__ __launch_bounds__(512, 1) void gemm10(const u16* __restrict__ A,
                                                 const u16* __restrict__ BT,
                                                 const float* __restrict__ bias,
                                                 float* __restrict__ outF,
                                                 u16* __restrict__ outB,
                                                 int M, int N, int K) {
  constexpr int BM = 256;
  constexpr int WN = 8 / WM;
  constexpr int MT = (BM / WM) / 32;  // row-tiles per wave (4 or 2)
  constexpr int NT = (BN / WN) / 32;  // col-tiles per wave (2)
  constexpr int BLB = BN / 128;       // B gload_lds per thread per half
  constexpr int LH = 2 + BLB;         // loads per half (A + B)
  __shared__ __align__(16) u16 Al[2][2][BM * 32];
  __shared__ __align__(16) u16 Bl[2][2][BN * 32];
  const int tid = threadIdx.x;
  const int w = tid >> 6, l = tid & 63;
  const int wr = w / WN, wc = w % WN;
  const int l31 = l & 31, hi = l >> 5;

  // XCD mapping: each XCD owns nx/8 contiguous bx (A slabs), streams by
  const int nx = M >> 8;
  const int gpx = nx >> 3;
  const int hgt = blockIdx.x;
  const int xcd = hgt & 7, j = hgt >> 3;
  const int bx = xcd * gpx + (j % gpx);
  const int by = j / gpx;
  const long m0 = (long)bx * BM, n0 = (long)by * BN;

  const int nt = K >> 6;

  const u16* baseA[2];
#pragma unroll
  for (int rr = 0; rr < 2; rr++) {
    int e = rr * 512 + tid, row = e >> 2;
    int kk = ((e & 3) - (row >> 1)) & 3;
    baseA[rr] = A + (m0 + row) * (long)K + kk * 8;
  }
  const u16* baseB[BLB];
#pragma unroll
  for (int rr = 0; rr < BLB; rr++) {
    int e = rr * 512 + tid, row = e >> 2;
    int kk = ((e & 3) - (row >> 1)) & 3;
    baseB[rr] = BT + (n0 + row) * (long)K + kk * 8;
  }

  auto stage = [&](int buf, int kh, int t) {
    if (t < nt) {
#pragma unroll
      for (int rr = 0; rr < 2; rr++)
        gload_lds16(baseA[rr] + (long)t * 64 + kh * 32, &Al[buf][kh][(rr * 512 + tid) * 8]);
#pragma unroll
      for (int rr = 0; rr < BLB; rr++)
        gload_lds16(baseB[rr] + (long)t * 64 + kh * 32, &Bl[buf][kh][(rr * 512 + tid) * 8]);
    }
  };

  f32x16 acc[MT][NT];
#pragma unroll
  for (int i = 0; i < MT; i++)
#pragma unroll
    for (int nn = 0; nn < NT; nn++)
#pragma unroll
      for (int r = 0; r < 16; r++) acc[i][nn][r] = 0.f;

  // prologue: 3 halves in flight
  stage(0, 0, 0); stage(0, 1, 0); stage(1, 0, 1);
  wait_vm<2 * LH>();
  SBAR(); __builtin_amdgcn_s_barrier(); SBAR();

  for (int t = 0; t < nt; ++t) {
    const int bt = t & 1, nb = bt ^ 1;
#pragma unroll
    for (int kh = 0; kh < 2; kh++) {
      const u16* Ah = &Al[bt][kh][0];
      const u16* Bh = &Bl[bt][kh][0];
      short8 bfr[NT][2], afr[MT][2];
      // pinned order: b[*][0], b[*][1], a[*][0], a[*][1]
#pragma unroll
      for (int nn = 0; nn < NT; nn++) {
        int row = wc * (BN / WN) + nn * 32 + l31;
        bfr[nn][0] = ds_read128(lds_off(&Bh[row * 32 + (((hi + (row >> 1)) & 3) << 3)]));
      }
#pragma unroll
      for (int nn = 0; nn < NT; nn++) {
        int row = wc * (BN / WN) + nn * 32 + l31;
        bfr[nn][1] = ds_read128(lds_off(&Bh[row * 32 + (((2 + hi + (row >> 1)) & 3) << 3)]));
      }
#pragma unroll
      for (int mm = 0; mm < MT; mm++) {
        int row = wr * (BM / WM) + mm * 32 + l31;
        afr[mm][0] = ds_read128(lds_off(&Ah[row * 32 + (((hi + (row >> 1)) & 3) << 3)]));
      }
#pragma unroll
      for (int mm = 0; mm < MT; mm++) {
        int row = wr * (BM / WM) + mm * 32 + l31;
        afr[mm][1] = ds_read128(lds_off(&Ah[row * 32 + (((2 + hi + (row >> 1)) & 3) << 3)]));
      }
      if (kh == 0) stage(nb, 1, t + 1); else stage(bt, 0, t + 2);
      __builtin_amdgcn_s_setprio(1);
      lgkm_gate(MT);  // b[*][0..1] + a[*][0] landed; a[*][1] still in flight
      SBAR();
#pragma unroll
      for (int mm = 0; mm < MT; mm++)
#pragma unroll
        for (int nn = 0; nn < NT; nn++)
          acc[mm][nn] = __builtin_amdgcn_mfma_f32_32x32x16_bf16(afr[mm][0], bfr[nn][0], acc[mm][nn], 0, 0, 0);
      lgkm_gate(0);
      SBAR();
#pragma unroll
      for (int mm = 0; mm < MT; mm++)
#pragma unroll
        for (int nn = 0; nn < NT; nn++)
          acc[mm][nn] = __builtin_amdgcn_mfma_f32_32x32x16_bf16(afr[mm][1], bfr[nn][1], acc[mm][nn], 0, 0, 0);
      __builtin_amdgcn_s_setprio(0);
      if (kh == 0) {
        if (t == nt - 1) wait_vm<0>(); else wait_vm<2 * LH>();
      } else {
        if (t + 2 < nt) wait_vm<2 * LH>();
        else if (t + 1 < nt) wait_vm<LH>();
      }
      SBAR(); __builtin_amdgcn_s_barrier(); SBAR();
    }
  }

  // epilogue: C layout col=lane&31, row=(reg&3)+8*(reg>>2)+4*hi
  float bv[NT];
#pragma unroll
  for (int nn = 0; nn < NT; nn++)
    bv[nn] = bias ? bias[n0 + wc * (BN / WN) + nn * 32 + l31] : 0.f;
#pragma unroll
  for (int mm = 0; mm < MT; mm++) {
#pragma unroll
    for (int r = 0; r < 16; r++) {
      const int rl = (r & 3) + 8 * (r >> 2) + 4 * hi;
      const long row = m0 + wr * (BM / WM) + mm * 32 + rl;
#pragma unroll
      for (int nn = 0; nn < NT; nn++) {
        const long col = n0 + wc * (BN / WN) + nn * 32 + l31;
        float v = acc[mm][nn][r] + bv[nn];
        if (GELU) v = 0.5f * v * (1.f + erff(v * 0.70710678118654752f));
        if (outF) outF[row * N + col] = v;
        if (outB) outB[row * N + col] = f2bf(v);
      }
    }
  }
}

// ---------- flash attention v4: swapped-operand + T13 defer-max + T5 setprio ----------
template <bool CAUSAL>
__global__ __launch_bounds__(256, 4) void attn4(const u16* __restrict__ qb, long q_bstride, int q_rstride,
                                                const u16* __restrict__ kbp, long k_bstride, int k_rstride,
                                                const u16* __restrict__ vt,
                                                u16* __restrict__ yb, long y_bstride, int y_rstride,
                                                int Nk, int H) {
  __shared__ __align__(16) u16 Kl[2][2048];
  __shared__ __align__(16) u16 Vl[2][2048];
  const int tid = threadIdx.x;
  const int w = tid >> 6, l = tid & 63;
  const int qi = l & 31, hi = l >> 5;

  const int nwg = gridDim.x;
  const int chunk = nwg >> 3;
  const int nb = (blockIdx.x & 7) * chunk + (blockIdx.x >> 3);
  const int bh = nb >> 3;
  const int bx6 = nb & 7;
  const int bx = (bx6 & 1) ? (7 - (bx6 >> 1)) : (bx6 >> 1);
  const int b = bh / H, h = bh % H;
  const int qr0 = bx * 128 + w * 32;
  const u16* qp = qb + (long)b * q_bstride + h * 64;
  const u16* kp = kbp + (long)b * k_bstride + h * 64;
  const u16* vp = vt + (long)bh * 64 * Nk;
  const float CL = 0.125f * 1.44269504088896340736f;
  const float DTHR = 8.0f / CL;  // defer-max threshold in raw-score units

  const u16* qrow = qp + (long)(qr0 + qi) * q_rstride + hi * 8;
  short8 qf0 = *(const short8*)(qrow);
  short8 qf1 = *(const short8*)(qrow + 16);
  short8 qf2 = *(const short8*)(qrow + 32);
  short8 qf3 = *(const short8*)(qrow + 48);

  f32x16 ot0, ot1;
#pragma unroll
  for (int i = 0; i < 16; i++) { ot0[i] = 0.f; ot1[i] = 0.f; }
  float m_run = -INFINITY, l_run = 0.f;

  const int krow_ = tid >> 3, kcb_ = (tid & 7) ^ (krow_ & 7);
  const int vrow_ = tid >> 2, vcb_ = (tid & 3) ^ (vrow_ & 3);
  const u16* kg = kp + (long)krow_ * k_rstride + kcb_ * 8;
  const u16* vg = vp + (long)vrow_ * Nk + vcb_ * 8;

  const int ntiles = CAUSAL ? (bx * 4 + 4) : (Nk >> 5);
  const int mytile = bx * 4 + w;

  gload_lds16(kg, &Kl[0][tid * 8]);
  gload_lds16(vg, &Vl[0][tid * 8]);
  __syncthreads();

  for (int t = 0; t < ntiles; ++t) {
    const int cur = t & 1;
    if (t + 1 < ntiles) {
      gload_lds16(kg + (t + 1) * 32 * (long)k_rstride, &Kl[cur ^ 1][tid * 8]);
      gload_lds16(vg + (t + 1) * 32, &Vl[cur ^ 1][tid * 8]);
    }
    if (!CAUSAL || t <= mytile) {
      const int kb0 = t * 32;
      const bool dmask = CAUSAL && (t == mytile);
      short8 kf[4];
#pragma unroll
      for (int ks = 0; ks < 4; ks++)
        kf[ks] = *(const short8*)&Kl[cur][(qi << 6) + (((2 * ks + hi) ^ (qi & 7)) << 3)];
      f32x16 sc;
#pragma unroll
      for (int i = 0; i < 16; i++) sc[i] = 0.f;
      __builtin_amdgcn_s_setprio(1);
      sc = __builtin_amdgcn_mfma_f32_32x32x16_bf16(kf[0], qf0, sc, 0, 0, 0);
      sc = __builtin_amdgcn_mfma_f32_32x32x16_bf16(kf[1], qf1, sc, 0, 0, 0);
      sc = __builtin_amdgcn_mfma_f32_32x32x16_bf16(kf[2], qf2, sc, 0, 0, 0);
      sc = __builtin_amdgcn_mfma_f32_32x32x16_bf16(kf[3], qf3, sc, 0, 0, 0);
      __builtin_amdgcn_s_setprio(0);
      if (dmask) {
#pragma unroll
        for (int r = 0; r < 16; r++) {
          int key = kb0 + (r & 3) + 8 * (r >> 2) + 4 * hi;
          if (key > qr0 + qi) sc[r] = -INFINITY;
        }
      }
      float mx = sc[0];
#pragma unroll
      for (int r = 1; r < 16; r++) mx = fmaxf(mx, sc[r]);
      { float a = mx, bb2 = mx; plswapf(a, bb2); mx = fmaxf(a, bb2); }
      // T13 defer-max: only rescale when some lane's max grew past threshold
      if (__any(mx > m_run + DTHR)) {
        float mnew = fmaxf(m_run, mx);
        float alpha = exp2f((m_run - mnew) * CL);
        m_run = mnew;
        l_run *= alpha;
#pragma unroll
        for (int i = 0; i < 16; i++) { ot0[i] *= alpha; ot1[i] *= alpha; }
      }
      float p[16];
      float ssum = 0.f;
#pragma unroll
      for (int r = 0; r < 16; r++) { p[r] = exp2f((sc[r] - m_run) * CL); ssum += p[r]; }
      { float a = ssum, bb2 = ssum; plswapf(a, bb2); ssum = a + bb2; }
      l_run += ssum;
      u32 w0 = cvtpk_bf16(p[0], p[1]);
      u32 w1 = cvtpk_bf16(p[2], p[3]);
      u32 w2 = cvtpk_bf16(p[4], p[5]);
      u32 w3 = cvtpk_bf16(p[6], p[7]);
      plswap32(w0, w2);
      plswap32(w1, w3);
      u32 w4 = cvtpk_bf16(p[8], p[9]);
      u32 w5 = cvtpk_bf16(p[10], p[11]);
      u32 w6 = cvtpk_bf16(p[12], p[13]);
      u32 w7 = cvtpk_bf16(p[14], p[15]);
      plswap32(w4, w6);
      plswap32(w5, w7);
      union { u32 u[4]; short8 s; } ua0, ua1;
      ua0.u[0] = w0; ua0.u[1] = w1; ua0.u[2] = w2; ua0.u[3] = w3;
      ua1.u[0] = w4; ua1.u[1] = w5; ua1.u[2] = w6; ua1.u[3] = w7;
      short8 va00 = *(const short8*)&Vl[cur][(qi << 5) + (((hi) ^ (qi & 3)) << 3)];
      short8 va01 = *(const short8*)&Vl[cur][(qi << 5) + (((2 + hi) ^ (qi & 3)) << 3)];
      short8 va10 = *(const short8*)&Vl[cur][((qi + 32) << 5) + (((hi) ^ (qi & 3)) << 3)];
      short8 va11 = *(const short8*)&Vl[cur][((qi + 32) << 5) + (((2 + hi) ^ (qi & 3)) << 3)];
      __builtin_amdgcn_s_setprio(1);
      ot0 = __builtin_amdgcn_mfma_f32_32x32x16_bf16(va00, ua0.s, ot0, 0, 0, 0);
      ot0 = __builtin_amdgcn_mfma_f32_32x32x16_bf16(va01, ua1.s, ot0, 0, 0, 0);
      ot1 = __builtin_amdgcn_mfma_f32_32x32x16_bf16(va10, ua0.s, ot1, 0, 0, 0);
      ot1 = __builtin_amdgcn_mfma_f32_32x32x16_bf16(va11, ua1.s, ot1, 0, 0, 0);
      __builtin_amdgcn_s_setprio(0);
    }
    __syncthreads();
  }

  float inv = 1.f / l_run;
  u16* yp = yb + (long)b * y_bstride + h * 64 + (long)(qr0 + qi) * y_rstride;
#pragma unroll
  for (int g = 0; g < 4; g++) {
    uint2 s0;
    s0.x = cvtpk_bf16(ot0[4 * g + 0] * inv, ot0[4 * g + 1] * inv);
    s0.y = cvtpk_bf16(ot0[4 * g + 2] * inv, ot0[4 * g + 3] * inv);
    *(uint2*)(yp + 8 * g + 4 * hi) = s0;
    uint2 s1;
    s1.x = cvtpk_bf16(ot1[4 * g + 0] * inv, ot1[4 * g + 1] * inv);
    s1.y = cvtpk_bf16(ot1[4 * g + 2] * inv, ot1[4 * g + 3] * inv);
    *(uint2*)(yp + 32 + 8 * g + 4 * hi) = s1;
  }
}

// ---------- layernorm, all-bf16 chain ----------
__global__ __launch_bounds__(256) void ln_b(const u16* __restrict__ x,
                                            const u16* __restrict__ res,
                                            const float* __restrict__ g,
                                            const float* __restrict__ bb,
                                            u16* __restrict__ resOut,
                                            float* __restrict__ outF,
                                            u16* __restrict__ outB, int C) {
  __shared__ float red[8];
  long row = blockIdx.x;
  int i0 = threadIdx.x * 4;
  unsigned long long pk = *(const unsigned long long*)(x + row * C + i0);
  float x0 = bf2f((u16)pk), x1 = bf2f((u16)(pk >> 16));
  float x2 = bf2f((u16)(pk >> 32)), x3 = bf2f((u16)(pk >> 48));
  if (res) {
    unsigned long long rk = *(const unsigned long long*)(res + row * C + i0);
    x0 += bf2f((u16)rk); x1 += bf2f((u16)(rk >> 16));
    x2 += bf2f((u16)(rk >> 32)); x3 += bf2f((u16)(rk >> 48));
  }
  if (resOut) {
    unsigned long long p = (unsigned long long)f2bf(x0) |
                           ((unsigned long long)f2bf(x1) << 16) |
                           ((unsigned long long)f2bf(x2) << 32) |
                           ((unsigned long long)f2bf(x3) << 48);
    *(unsigned long long*)(resOut + row * C + i0) = p;
  }
  float s = x0 + x1 + x2 + x3;
  float sq = x0 * x0 + x1 * x1 + x2 * x2 + x3 * x3;
#pragma unroll
  for (int off = 1; off < 64; off <<= 1) {
    s += __shfl_xor(s, off, 64);
    sq += __shfl_xor(sq, off, 64);
  }
  int w = threadIdx.x >> 6, l = threadIdx.x & 63;
  if (l == 0) { red[w] = s; red[4 + w] = sq; }
  __syncthreads();
  s = red[0] + red[1] + red[2] + red[3];
  sq = red[4] + red[5] + red[6] + red[7];
  float mean = s * (1.f / 1024.f);
  float var = sq * (1.f / 1024.f) - mean * mean;
  float rstd = rsqrtf(var + 1e-5f);
  float4 gv = *(const float4*)(g + i0);
  float4 bv = *(const float4*)(bb + i0);
  float o0 = (x0 - mean) * rstd * gv.x + bv.x;
  float o1 = (x1 - mean) * rstd * gv.y + bv.y;
  float o2 = (x2 - mean) * rstd * gv.z + bv.z;
  float o3 = (x3 - mean) * rstd * gv.w + bv.w;
  if (outF) {
    float4 ov; ov.x = o0; ov.y = o1; ov.z = o2; ov.w = o3;
    *(float4*)(outF + row * C + i0) = ov;
  }
  if (outB) {
    unsigned long long p = (unsigned long long)f2bf(o0) |
                           ((unsigned long long)f2bf(o1) << 16) |
                           ((unsigned long long)f2bf(o2) << 32) |
                           ((unsigned long long)f2bf(o3) << 48);
    *(unsigned long long*)(outB + row * C + i0) = p;
  }
}

// ---------- launcher ----------
extern "C" void kernel_launch(void* const* d_in, const int* in_sizes, int n_in,
                              void* d_out, int out_size, void* d_ws, size_t ws_size,
                              hipStream_t stream) {
  const int B = 8, N = 1024, T = 512, C = 1024, H = 16;
  const float* prev = (const float*)d_in[0];
  const float* enc = (const float*)d_in[1];
  const float* sa_w = (const float*)d_in[2];
  const float* sa_b = (const float*)d_in[3];
  const float* sa_pw = (const float*)d_in[4];
  const float* sa_pb = (const float*)d_in[5];
  const float* caq_w = (const float*)d_in[6];
  const float* caq_b = (const float*)d_in[7];
  const float* cakv_w = (const float*)d_in[8];
  const float* cakv_b = (const float*)d_in[9];
  const float* ca_pw = (const float*)d_in[10];
  const float* ca_pb = (const float*)d_in[11];
  const float* fc_w = (const float*)d_in[12];
  const float* fc_b = (const float*)d_in[13];
  const float* proj_w = (const float*)d_in[14];
  const float* proj_b = (const float*)d_in[15];
  const float* ln1_g = (const float*)d_in[16];
  const float* ln1_b = (const float*)d_in[17];
  const float* ln2_g = (const float*)d_in[18];
  const float* ln2_b = (const float*)d_in[19];
  const float* ln3_g = (const float*)d_in[20];
  const float* ln3_b = (const float*)d_in[21];

  char* ws = (char*)d_ws;
  u16* wT_sa   = (u16*)(ws + 0);               // [3072,1024]
  u16* wT_sapw = (u16*)(ws + 6291456);         // [1024,1024]
  u16* wT_caq  = (u16*)(ws + 8388608);         // [1024,1024]
  u16* wT_cakv = (u16*)(ws + 10485760);        // [2048,1024]
  u16* wT_capw = (u16*)(ws + 14680064);        // [1024,1024]
  u16* wT_fc   = (u16*)(ws + 16777216);        // [4096,1024]
  u16* wT_proj = (u16*)(ws + 25165824);        // [1024,4096]
  u16* abf   = (u16*)(ws + 33554432);
  u16* encbf = (u16*)(ws + 50331648);
  u16* qkv   = (u16*)(ws + 58720256);
  u16* vt1   = (u16*)(ws + 109051904);
  u16* ybf   = (u16*)(ws + 125829120);
  u16* pbf   = (u16*)(ws + 142606336);         // GEMM bf16 out (reused 3x)
  u16* xres  = (u16*)(ws + 176160768);         // bf16 residual state (x2)
  u16* x1bf  = (u16*)(ws + 209715200);         // LN outputs
  u16* kvbf  = (u16*)(ws + 226492416);
  u16* y2bf  = abf;
  u16* vt2   = encbf;
  u16* q2bf  = ybf;
  u16* hbf   = qkv;

  cvt_f32_bf16<<<8192, 256, 0, stream>>>(prev, abf, (long)B * N * C);
  cvt_f32_bf16<<<4096, 256, 0, stream>>>(enc, encbf, (long)B * T * C);
  wtrans<<<dim3(96, 32), dim3(32, 8), 0, stream>>>(sa_w, wT_sa, 1024, 3072);
  wtrans<<<dim3(32, 32), dim3(32, 8), 0, stream>>>(sa_pw, wT_sapw, 1024, 1024);
  wtrans<<<dim3(32, 32), dim3(32, 8), 0, stream>>>(caq_w, wT_caq, 1024, 1024);
  wtrans<<<dim3(64, 32), dim3(32, 8), 0, stream>>>(cakv_w, wT_cakv, 1024, 2048);
  wtrans<<<dim3(32, 32), dim3(32, 8), 0, stream>>>(ca_pw, wT_capw, 1024, 1024);
  wtrans<<<dim3(128, 32), dim3(32, 8), 0, stream>>>(fc_w, wT_fc, 1024, 4096);
  wtrans<<<dim3(32, 128), dim3(32, 8), 0, stream>>>(proj_w, wT_proj, 4096, 1024);
  // qkv: M=8192 N=3072 K=1024
  gemm10<128, 4, 0><<<768, 512, 0, stream>>>(abf, wT_sa, sa_b, nullptr, qkv, 8192, 3072, 1024);
  vtrans<<<dim3(16, 128), 256, 0, stream>>>(qkv, vt1, 1024, 3 * C, 2 * C, H);
  attn4<true><<<dim3(1024), 256, 0, stream>>>(qkv, (long)N * 3 * C, 3 * C,
                                              qkv + C, (long)N * 3 * C, 3 * C,
                                              vt1, ybf, (long)N * C, C, N, H);
  // self-attn proj -> bf16 only
  gemm10<128, 4, 0><<<256, 512, 0, stream>>>(ybf, wT_sapw, sa_pb, nullptr, pbf, 8192, 1024, 1024);
  // LN1: x1bf = LN(pbf)  (x1bf doubles as LN2's residual)
  ln_b<<<8192, 256, 0, stream>>>(pbf, nullptr, ln1_g, ln1_b, nullptr, nullptr, x1bf, C);
  gemm10<128, 4, 0><<<256, 512, 0, stream>>>(x1bf, wT_caq, caq_b, nullptr, q2bf, 8192, 1024, 1024);
  gemm10<128, 4, 0><<<256, 512, 0, stream>>>(encbf, wT_cakv, cakv_b, nullptr, kvbf, 4096, 2048, 1024);
  vtrans<<<dim3(8, 128), 256, 0, stream>>>(kvbf, vt2, 512, 2 * C, C, H);
  attn4<false><<<dim3(1024), 256, 0, stream>>>(q2bf, (long)N * C, C,
                                               kvbf, (long)T * 2 * C, 2 * C,
                                               vt2, y2bf, (long)N * C, C, T, H);
  // cross proj -> bf16 only
  gemm10<128, 4, 0><<<256, 512, 0, stream>>>(y2bf, wT_capw, ca_pb, nullptr, pbf, 8192, 1024, 1024);
  // LN2: x2 = x1bf + pbf -> xres (bf16); LN out -> x1bf (in-place safe, row-local)
  ln_b<<<8192, 256, 0, stream>>>(pbf, x1bf, ln2_g, ln2_b, xres, nullptr, x1bf, C);
  // fc: M=8192 N=4096 K=1024, GELU
  gemm10<256, 2, 1><<<512, 512, 0, stream>>>(x1bf, wT_fc, fc_b, nullptr, hbf, 8192, 4096, 1024);
  // proj: M=8192 N=1024 K=4096 -> bf16 only
  gemm10<128, 4, 0><<<256, 512, 0, stream>>>(hbf, wT_proj, proj_b, nullptr, pbf, 8192, 1024, 4096);
  // LN3: d_out = LN(pbf + xres) (f32)
  ln_b<<<8192, 256, 0, stream>>>(pbf, xres, ln3_g, ln3_b, nullptr, (float*)d_out, nullptr, C);
}

// Round 17
// 512.608 us; speedup vs baseline: 1.0803x; 1.0803x over previous
//
#include <hip/hip_runtime.h>

typedef unsigned short u16;
typedef unsigned int u32;
typedef __attribute__((ext_vector_type(8))) short short8;
typedef __attribute__((ext_vector_type(4))) float f32x4;
typedef __attribute__((ext_vector_type(16))) float f32x16;

// ---------- helpers ----------
__device__ __forceinline__ u16 f2bf(float f) {
  union { float f; unsigned int u; } v; v.f = f;
  unsigned int r = v.u + 0x7FFFu + ((v.u >> 16) & 1u);  // RNE
  return (u16)(r >> 16);
}
__device__ __forceinline__ float bf2f(u16 b) {
  union { unsigned int u; float f; } v; v.u = ((unsigned int)b) << 16;
  return v.f;
}

__device__ __forceinline__ void gload_lds16(const void* g, void* l) {
  __builtin_amdgcn_global_load_lds((const __attribute__((address_space(1))) void*)g,
                                   (__attribute__((address_space(3))) void*)l, 16, 0, 0);
}

__device__ __forceinline__ u32 cvtpk_bf16(float lo, float hi) {
  u32 r;
  asm("v_cvt_pk_bf16_f32 %0, %1, %2" : "=v"(r) : "v"(lo), "v"(hi));
  return r;
}

__device__ __forceinline__ void plswap32(u32& a, u32& b) {
#if __has_builtin(__builtin_amdgcn_permlane32_swap)
  auto r = __builtin_amdgcn_permlane32_swap((int)a, (int)b, false, false);
  a = (u32)r[0]; b = (u32)r[1];
#else
  asm volatile("v_permlane32_swap_b32 %0, %1" : "+v"(a), "+v"(b));
#endif
}

__device__ __forceinline__ void plswapf(float& a, float& b) {
  union { float f; u32 u; } x, y; x.f = a; y.f = b;
  plswap32(x.u, y.u);
  a = x.f; b = y.f;
}

template <int N>
__device__ __forceinline__ void wait_vm() {
  if constexpr (N == 0) asm volatile("s_waitcnt vmcnt(0)" ::: "memory");
  else if constexpr (N == 3) asm volatile("s_waitcnt vmcnt(3)" ::: "memory");
  else if constexpr (N == 4) asm volatile("s_waitcnt vmcnt(4)" ::: "memory");
  else if constexpr (N == 6) asm volatile("s_waitcnt vmcnt(6)" ::: "memory");
  else if constexpr (N == 8) asm volatile("s_waitcnt vmcnt(8)" ::: "memory");
}
// counted lgkm gate; n is compile-time constant after unrolling
__device__ __forceinline__ void lgkm_gate(int n) {
  switch (n) {
    case 0: asm volatile("s_waitcnt lgkmcnt(0)" ::: "memory"); break;
    case 1: asm volatile("s_waitcnt lgkmcnt(1)" ::: "memory"); break;
    case 2: asm volatile("s_waitcnt lgkmcnt(2)" ::: "memory"); break;
    case 3: asm volatile("s_waitcnt lgkmcnt(3)" ::: "memory"); break;
    case 4: asm volatile("s_waitcnt lgkmcnt(4)" ::: "memory"); break;
    case 5: asm volatile("s_waitcnt lgkmcnt(5)" ::: "memory"); break;
    case 6: asm volatile("s_waitcnt lgkmcnt(6)" ::: "memory"); break;
    default: asm volatile("s_waitcnt lgkmcnt(7)" ::: "memory"); break;
  }
}
#define SBAR() __builtin_amdgcn_sched_barrier(0)

// order-pinned LDS read (asm volatile => issue order preserved for counted gates)
__device__ __forceinline__ u32 lds_off(const void* p) {
  return (u32)(size_t)(const __attribute__((address_space(3))) void*)p;
}
__device__ __forceinline__ short8 ds_read128(u32 off) {
  short8 d;
  asm volatile("ds_read_b128 %0, %1" : "=v"(d) : "v"(off));
  return d;
}

// ---------- f32 -> bf16 convert ----------
__global__ __launch_bounds__(256) void cvt_f32_bf16(const float* __restrict__ in,
                                                    u16* __restrict__ out, long n) {
  long i = ((long)blockIdx.x * 256 + threadIdx.x) * 4;
  if (i + 3 < n) {
    float4 v = *(const float4*)(in + i);
    unsigned long long p = (unsigned long long)f2bf(v.x) |
                           ((unsigned long long)f2bf(v.y) << 16) |
                           ((unsigned long long)f2bf(v.z) << 32) |
                           ((unsigned long long)f2bf(v.w) << 48);
    *(unsigned long long*)(out + i) = p;
  }
}

// ---------- weight transpose+convert: W[K,N] f32 -> WT[N,K] bf16 ----------
__global__ __launch_bounds__(256) void wtrans(const float* __restrict__ W,
                                              u16* __restrict__ WT, int K, int N) {
  __shared__ float t[32][33];
  int n0 = blockIdx.x * 32, k0 = blockIdx.y * 32;
  int tx = threadIdx.x, ty = threadIdx.y;
#pragma unroll
  for (int r = 0; r < 4; r++)
    t[ty + r * 8][tx] = W[(long)(k0 + ty + r * 8) * N + n0 + tx];
  __syncthreads();
#pragma unroll
  for (int r = 0; r < 4; r++)
    WT[(long)(n0 + ty + r * 8) * K + k0 + tx] = f2bf(t[tx][ty + r * 8]);
}

// ---------- V transpose: [b, n, head_off + h*64 + d] -> [bh][d][n] ----------
__global__ __launch_bounds__(256) void vtrans(const u16* __restrict__ src,
                                              u16* __restrict__ dst,
                                              int rows, int rstride, int head_off, int H) {
  __shared__ u16 t[64][65];
  int bh = blockIdx.y;
  int b = bh / H, h = bh % H;
  long n0 = (long)blockIdx.x * 64;
  const u16* s = src + (long)b * rows * rstride + head_off + h * 64;
  int q = threadIdx.x >> 6, ln = threadIdx.x & 63;
#pragma unroll
  for (int r = 0; r < 16; r++) {
    int nl = q * 16 + r;
    t[nl][ln] = s[(n0 + nl) * (long)rstride + ln];
  }
  __syncthreads();
  u16* d = dst + (long)bh * 64 * rows;
#pragma unroll
  for (int r = 0; r < 16; r++) {
    int dd = q * 16 + r;
    d[(long)dd * rows + n0 + ln] = t[ln][dd];
  }
}

// ---------- gemm4 (best measured): merged phase + pipelined counted-lgkm gates ----------
template <int BN, int WM, int GELU>
__global__ __launch_bounds__(512, 1) void gemm4(const u16* __restrict__ A,
                                                const u16* __restrict__ BT,
                                                const float* __restrict__ bias,
                                                float* __restrict__ outF,
                                                u16* __restrict__ outB,
                                                int M, int N, int K) {
  constexpr int BM = 256;
  constexpr int WN = 8 / WM;
  constexpr int MR = BM / (16 * WM);
  constexpr int NR = BN / (16 * WN);
  constexpr int BLB = BN / 128;   // B gload_lds per thread per half
  constexpr int LH = 2 + BLB;     // loads per half (A + B)
  __shared__ __align__(16) u16 Al[2][2][BM * 32];
  __shared__ __align__(16) u16 Bl[2][2][BN * 32];
  const int tid = threadIdx.x;
  const int w = tid >> 6, l = tid & 63;
  const int wr = w / WN, wc = w % WN;
  const int lr = l & 15, lg = l >> 4;

  // XCD mapping: each XCD owns nx/8 contiguous bx (A slabs), streams by
  const int nx = M >> 8;
  const int gpx = nx >> 3;
  const int hgt = blockIdx.x;
  const int xcd = hgt & 7, j = hgt >> 3;
  const int bx = xcd * gpx + (j % gpx);
  const int by = j / gpx;
  const long m0 = (long)bx * BM, n0 = (long)by * BN;

  const int nt = K >> 6;

  const u16* baseA[2];
#pragma unroll
  for (int rr = 0; rr < 2; rr++) {
    int e = rr * 512 + tid, row = e >> 2;
    int kk = ((e & 3) - (row >> 1)) & 3;
    baseA[rr] = A + (m0 + row) * (long)K + kk * 8;
  }
  const u16* baseB[BLB];
#pragma unroll
  for (int rr = 0; rr < BLB; rr++) {
    int e = rr * 512 + tid, row = e >> 2;
    int kk = ((e & 3) - (row >> 1)) & 3;
    baseB[rr] = BT + (n0 + row) * (long)K + kk * 8;
  }

  auto stage = [&](int buf, int kh, int t) {
    if (t < nt) {
#pragma unroll
      for (int rr = 0; rr < 2; rr++)
        gload_lds16(baseA[rr] + (long)t * 64 + kh * 32, &Al[buf][kh][(rr * 512 + tid) * 8]);
#pragma unroll
      for (int rr = 0; rr < BLB; rr++)
        gload_lds16(baseB[rr] + (long)t * 64 + kh * 32, &Bl[buf][kh][(rr * 512 + tid) * 8]);
    }
  };

  f32x4 acc[MR][NR];
#pragma unroll
  for (int i = 0; i < MR; i++)
#pragma unroll
    for (int nn = 0; nn < NR; nn++) acc[i][nn] = (f32x4){0.f, 0.f, 0.f, 0.f};

  // prologue: 3 halves in flight
  stage(0, 0, 0); stage(0, 1, 0); stage(1, 0, 1);
  wait_vm<2 * LH>();
  SBAR(); __builtin_amdgcn_s_barrier(); SBAR();

  for (int t = 0; t < nt; ++t) {
    const int bt = t & 1, nb = bt ^ 1;
#pragma unroll
    for (int kh = 0; kh < 2; kh++) {
      const u16* Ah = &Al[bt][kh][0];
      const u16* Bh = &Bl[bt][kh][0];
      short8 bf[NR], af[MR];
#pragma unroll
      for (int nn = 0; nn < NR; nn++) {
        int row = wc * (BN / WN) + nn * 16 + lr;
        bf[nn] = ds_read128(lds_off(&Bh[row * 32 + (((lg + (row >> 1)) & 3) << 3)]));
      }
#pragma unroll
      for (int mm = 0; mm < MR; mm++) {
        int row = wr * (BM / WM) + mm * 16 + lr;
        af[mm] = ds_read128(lds_off(&Ah[row * 32 + (((lg + (row >> 1)) & 3) << 3)]));
      }
      if (kh == 0) stage(nb, 1, t + 1); else stage(bt, 0, t + 2);
      __builtin_amdgcn_s_setprio(1);
#pragma unroll
      for (int mm = 0; mm < MR; mm++) {
        lgkm_gate(MR - 1 - mm);
        SBAR();
#pragma unroll
        for (int nn = 0; nn < NR; nn++)
          acc[mm][nn] = __builtin_amdgcn_mfma_f32_16x16x32_bf16(af[mm], bf[nn], acc[mm][nn], 0, 0, 0);
      }
      __builtin_amdgcn_s_setprio(0);
      if (kh == 0) {
        if (t == nt - 1) wait_vm<0>(); else wait_vm<2 * LH>();
      } else {
        if (t + 2 < nt) wait_vm<2 * LH>();
        else if (t + 1 < nt) wait_vm<LH>();
      }
      SBAR(); __builtin_amdgcn_s_barrier(); SBAR();
    }
  }

  float bv[NR];
#pragma unroll
  for (int nn = 0; nn < NR; nn++)
    bv[nn] = bias ? bias[n0 + wc * (BN / WN) + nn * 16 + lr] : 0.f;
#pragma unroll
  for (int mm = 0; mm < MR; mm++) {
#pragma unroll
    for (int i = 0; i < 4; i++) {
      const long row = m0 + wr * (BM / WM) + mm * 16 + lg * 4 + i;
#pragma unroll
      for (int nn = 0; nn < NR; nn++) {
        const long col = n0 + wc * (BN / WN) + nn * 16 + lr;
        float v = acc[mm][nn][i] + bv[nn];
        if (GELU) v = 0.5f * v * (1.f + erff(v * 0.70710678118654752f));
        if (outF) outF[row * N + col] = v;
        if (outB) outB[row * N + col] = f2bf(v);
      }
    }
  }
}

// ---------- flash attention v4: swapped-operand + T13 defer-max + T5 setprio ----------
template <bool CAUSAL>
__global__ __launch_bounds__(256, 4) void attn4(const u16* __restrict__ qb, long q_bstride, int q_rstride,
                                                const u16* __restrict__ kbp, long k_bstride, int k_rstride,
                                                const u16* __restrict__ vt,
                                                u16* __restrict__ yb, long y_bstride, int y_rstride,
                                                int Nk, int H) {
  __shared__ __align__(16) u16 Kl[2][2048];
  __shared__ __align__(16) u16 Vl[2][2048];
  const int tid = threadIdx.x;
  const int w = tid >> 6, l = tid & 63;
  const int qi = l & 31, hi = l >> 5;

  const int nwg = gridDim.x;
  const int chunk = nwg >> 3;
  const int nb = (blockIdx.x & 7) * chunk + (blockIdx.x >> 3);
  const int bh = nb >> 3;
  const int bx6 = nb & 7;
  const int bx = (bx6 & 1) ? (7 - (bx6 >> 1)) : (bx6 >> 1);
  const int b = bh / H, h = bh % H;
  const int qr0 = bx * 128 + w * 32;
  const u16* qp = qb + (long)b * q_bstride + h * 64;
  const u16* kp = kbp + (long)b * k_bstride + h * 64;
  const u16* vp = vt + (long)bh * 64 * Nk;
  const float CL = 0.125f * 1.44269504088896340736f;
  const float DTHR = 8.0f / CL;  // defer-max threshold in raw-score units

  const u16* qrow = qp + (long)(qr0 + qi) * q_rstride + hi * 8;
  short8 qf0 = *(const short8*)(qrow);
  short8 qf1 = *(const short8*)(qrow + 16);
  short8 qf2 = *(const short8*)(qrow + 32);
  short8 qf3 = *(const short8*)(qrow + 48);

  f32x16 ot0, ot1;
#pragma unroll
  for (int i = 0; i < 16; i++) { ot0[i] = 0.f; ot1[i] = 0.f; }
  float m_run = -INFINITY, l_run = 0.f;

  const int krow_ = tid >> 3, kcb_ = (tid & 7) ^ (krow_ & 7);
  const int vrow_ = tid >> 2, vcb_ = (tid & 3) ^ (vrow_ & 3);
  const u16* kg = kp + (long)krow_ * k_rstride + kcb_ * 8;
  const u16* vg = vp + (long)vrow_ * Nk + vcb_ * 8;

  const int ntiles = CAUSAL ? (bx * 4 + 4) : (Nk >> 5);
  const int mytile = bx * 4 + w;

  gload_lds16(kg, &Kl[0][tid * 8]);
  gload_lds16(vg, &Vl[0][tid * 8]);
  __syncthreads();

  for (int t = 0; t < ntiles; ++t) {
    const int cur = t & 1;
    if (t + 1 < ntiles) {
      gload_lds16(kg + (t + 1) * 32 * (long)k_rstride, &Kl[cur ^ 1][tid * 8]);
      gload_lds16(vg + (t + 1) * 32, &Vl[cur ^ 1][tid * 8]);
    }
    if (!CAUSAL || t <= mytile) {
      const int kb0 = t * 32;
      const bool dmask = CAUSAL && (t == mytile);
      short8 kf[4];
#pragma unroll
      for (int ks = 0; ks < 4; ks++)
        kf[ks] = *(const short8*)&Kl[cur][(qi << 6) + (((2 * ks + hi) ^ (qi & 7)) << 3)];
      f32x16 sc;
#pragma unroll
      for (int i = 0; i < 16; i++) sc[i] = 0.f;
      __builtin_amdgcn_s_setprio(1);
      sc = __builtin_amdgcn_mfma_f32_32x32x16_bf16(kf[0], qf0, sc, 0, 0, 0);
      sc = __builtin_amdgcn_mfma_f32_32x32x16_bf16(kf[1], qf1, sc, 0, 0, 0);
      sc = __builtin_amdgcn_mfma_f32_32x32x16_bf16(kf[2], qf2, sc, 0, 0, 0);
      sc = __builtin_amdgcn_mfma_f32_32x32x16_bf16(kf[3], qf3, sc, 0, 0, 0);
      __builtin_amdgcn_s_setprio(0);
      if (dmask) {
#pragma unroll
        for (int r = 0; r < 16; r++) {
          int key = kb0 + (r & 3) + 8 * (r >> 2) + 4 * hi;
          if (key > qr0 + qi) sc[r] = -INFINITY;
        }
      }
      float mx = sc[0];
#pragma unroll
      for (int r = 1; r < 16; r++) mx = fmaxf(mx, sc[r]);
      { float a = mx, bb2 = mx; plswapf(a, bb2); mx = fmaxf(a, bb2); }
      // T13 defer-max: only rescale when some lane's max grew past threshold
      if (__any(mx > m_run + DTHR)) {
        float mnew = fmaxf(m_run, mx);
        float alpha = exp2f((m_run - mnew) * CL);
        m_run = mnew;
        l_run *= alpha;
#pragma unroll
        for (int i = 0; i < 16; i++) { ot0[i] *= alpha; ot1[i] *= alpha; }
      }
      float p[16];
      float ssum = 0.f;
#pragma unroll
      for (int r = 0; r < 16; r++) { p[r] = exp2f((sc[r] - m_run) * CL); ssum += p[r]; }
      { float a = ssum, bb2 = ssum; plswapf(a, bb2); ssum = a + bb2; }
      l_run += ssum;
      u32 w0 = cvtpk_bf16(p[0], p[1]);
      u32 w1 = cvtpk_bf16(p[2], p[3]);
      u32 w2 = cvtpk_bf16(p[4], p[5]);
      u32 w3 = cvtpk_bf16(p[6], p[7]);
      plswap32(w0, w2);
      plswap32(w1, w3);
      u32 w4 = cvtpk_bf16(p[8], p[9]);
      u32 w5 = cvtpk_bf16(p[10], p[11]);
      u32 w6 = cvtpk_bf16(p[12], p[13]);
      u32 w7 = cvtpk_bf16(p[14], p[15]);
      plswap32(w4, w6);
      plswap32(w5, w7);
      union { u32 u[4]; short8 s; } ua0, ua1;
      ua0.u[0] = w0; ua0.u[1] = w1; ua0.u[2] = w2; ua0.u[3] = w3;
      ua1.u[0] = w4; ua1.u[1] = w5; ua1.u[2] = w6; ua1.u[3] = w7;
      short8 va00 = *(const short8*)&Vl[cur][(qi << 5) + (((hi) ^ (qi & 3)) << 3)];
      short8 va01 = *(const short8*)&Vl[cur][(qi << 5) + (((2 + hi) ^ (qi & 3)) << 3)];
      short8 va10 = *(const short8*)&Vl[cur][((qi + 32) << 5) + (((hi) ^ (qi & 3)) << 3)];
      short8 va11 = *(const short8*)&Vl[cur][((qi + 32) << 5) + (((2 + hi) ^ (qi & 3)) << 3)];
      __builtin_amdgcn_s_setprio(1);
      ot0 = __builtin_amdgcn_mfma_f32_32x32x16_bf16(va00, ua0.s, ot0, 0, 0, 0);
      ot0 = __builtin_amdgcn_mfma_f32_32x32x16_bf16(va01, ua1.s, ot0, 0, 0, 0);
      ot1 = __builtin_amdgcn_mfma_f32_32x32x16_bf16(va10, ua0.s, ot1, 0, 0, 0);
      ot1 = __builtin_amdgcn_mfma_f32_32x32x16_bf16(va11, ua1.s, ot1, 0, 0, 0);
      __builtin_amdgcn_s_setprio(0);
    }
    __syncthreads();
  }

  float inv = 1.f / l_run;
  u16* yp = yb + (long)b * y_bstride + h * 64 + (long)(qr0 + qi) * y_rstride;
#pragma unroll
  for (int g = 0; g < 4; g++) {
    uint2 s0;
    s0.x = cvtpk_bf16(ot0[4 * g + 0] * inv, ot0[4 * g + 1] * inv);
    s0.y = cvtpk_bf16(ot0[4 * g + 2] * inv, ot0[4 * g + 3] * inv);
    *(uint2*)(yp + 8 * g + 4 * hi) = s0;
    uint2 s1;
    s1.x = cvtpk_bf16(ot1[4 * g + 0] * inv, ot1[4 * g + 1] * inv);
    s1.y = cvtpk_bf16(ot1[4 * g + 2] * inv, ot1[4 * g + 3] * inv);
    *(uint2*)(yp + 32 + 8 * g + 4 * hi) = s1;
  }
}

// ---------- layernorm, all-bf16 chain ----------
__global__ __launch_bounds__(256) void ln_b(const u16* __restrict__ x,
                                            const u16* __restrict__ res,
                                            const float* __restrict__ g,
                                            const float* __restrict__ bb,
                                            u16* __restrict__ resOut,
                                            float* __restrict__ outF,
                                            u16* __restrict__ outB, int C) {
  __shared__ float red[8];
  long row = blockIdx.x;
  int i0 = threadIdx.x * 4;
  unsigned long long pk = *(const unsigned long long*)(x + row * C + i0);
  float x0 = bf2f((u16)pk), x1 = bf2f((u16)(pk >> 16));
  float x2 = bf2f((u16)(pk >> 32)), x3 = bf2f((u16)(pk >> 48));
  if (res) {
    unsigned long long rk = *(const unsigned long long*)(res + row * C + i0);
    x0 += bf2f((u16)rk); x1 += bf2f((u16)(rk >> 16));
    x2 += bf2f((u16)(rk >> 32)); x3 += bf2f((u16)(rk >> 48));
  }
  if (resOut) {
    unsigned long long p = (unsigned long long)f2bf(x0) |
                           ((unsigned long long)f2bf(x1) << 16) |
                           ((unsigned long long)f2bf(x2) << 32) |
                           ((unsigned long long)f2bf(x3) << 48);
    *(unsigned long long*)(resOut + row * C + i0) = p;
  }
  float s = x0 + x1 + x2 + x3;
  float sq = x0 * x0 + x1 * x1 + x2 * x2 + x3 * x3;
#pragma unroll
  for (int off = 1; off < 64; off <<= 1) {
    s += __shfl_xor(s, off, 64);
    sq += __shfl_xor(sq, off, 64);
  }
  int w = threadIdx.x >> 6, l = threadIdx.x & 63;
  if (l == 0) { red[w] = s; red[4 + w] = sq; }
  __syncthreads();
  s = red[0] + red[1] + red[2] + red[3];
  sq = red[4] + red[5] + red[6] + red[7];
  float mean = s * (1.f / 1024.f);
  float var = sq * (1.f / 1024.f) - mean * mean;
  float rstd = rsqrtf(var + 1e-5f);
  float4 gv = *(const float4*)(g + i0);
  float4 bv = *(const float4*)(bb + i0);
  float o0 = (x0 - mean) * rstd * gv.x + bv.x;
  float o1 = (x1 - mean) * rstd * gv.y + bv.y;
  float o2 = (x2 - mean) * rstd * gv.z + bv.z;
  float o3 = (x3 - mean) * rstd * gv.w + bv.w;
  if (outF) {
    float4 ov; ov.x = o0; ov.y = o1; ov.z = o2; ov.w = o3;
    *(float4*)(outF + row * C + i0) = ov;
  }
  if (outB) {
    unsigned long long p = (unsigned long long)f2bf(o0) |
                           ((unsigned long long)f2bf(o1) << 16) |
                           ((unsigned long long)f2bf(o2) << 32) |
                           ((unsigned long long)f2bf(o3) << 48);
    *(unsigned long long*)(outB + row * C + i0) = p;
  }
}

// ---------- launcher ----------
extern "C" void kernel_launch(void* const* d_in, const int* in_sizes, int n_in,
                              void* d_out, int out_size, void* d_ws, size_t ws_size,
                              hipStream_t stream) {
  const int B = 8, N = 1024, T = 512, C = 1024, H = 16;
  const float* prev = (const float*)d_in[0];
  const float* enc = (const float*)d_in[1];
  const float* sa_w = (const float*)d_in[2];
  const float* sa_b = (const float*)d_in[3];
  const float* sa_pw = (const float*)d_in[4];
  const float* sa_pb = (const float*)d_in[5];
  const float* caq_w = (const float*)d_in[6];
  const float* caq_b = (const float*)d_in[7];
  const float* cakv_w = (const float*)d_in[8];
  const float* cakv_b = (const float*)d_in[9];
  const float* ca_pw = (const float*)d_in[10];
  const float* ca_pb = (const float*)d_in[11];
  const float* fc_w = (const float*)d_in[12];
  const float* fc_b = (const float*)d_in[13];
  const float* proj_w = (const float*)d_in[14];
  const float* proj_b = (const float*)d_in[15];
  const float* ln1_g = (const float*)d_in[16];
  const float* ln1_b = (const float*)d_in[17];
  const float* ln2_g = (const float*)d_in[18];
  const float* ln2_b = (const float*)d_in[19];
  const float* ln3_g = (const float*)d_in[20];
  const float* ln3_b = (const float*)d_in[21];

  char* ws = (char*)d_ws;
  u16* wT_sa   = (u16*)(ws + 0);               // [3072,1024]
  u16* wT_sapw = (u16*)(ws + 6291456);         // [1024,1024]
  u16* wT_caq  = (u16*)(ws + 8388608);         // [1024,1024]
  u16* wT_cakv = (u16*)(ws + 10485760);        // [2048,1024]
  u16* wT_capw = (u16*)(ws + 14680064);        // [1024,1024]
  u16* wT_fc   = (u16*)(ws + 16777216);        // [4096,1024]
  u16* wT_proj = (u16*)(ws + 25165824);        // [1024,4096]
  u16* abf   = (u16*)(ws + 33554432);
  u16* encbf = (u16*)(ws + 50331648);
  u16* qkv   = (u16*)(ws + 58720256);
  u16* vt1   = (u16*)(ws + 109051904);
  u16* ybf   = (u16*)(ws + 125829120);
  u16* pbf   = (u16*)(ws + 142606336);         // GEMM bf16 out (reused 3x)
  u16* xres  = (u16*)(ws + 176160768);         // bf16 residual state (x2)
  u16* x1bf  = (u16*)(ws + 209715200);         // LN outputs
  u16* kvbf  = (u16*)(ws + 226492416);
  u16* y2bf  = abf;
  u16* vt2   = encbf;
  u16* q2bf  = ybf;
  u16* hbf   = qkv;

  cvt_f32_bf16<<<8192, 256, 0, stream>>>(prev, abf, (long)B * N * C);
  cvt_f32_bf16<<<4096, 256, 0, stream>>>(enc, encbf, (long)B * T * C);
  wtrans<<<dim3(96, 32), dim3(32, 8), 0, stream>>>(sa_w, wT_sa, 1024, 3072);
  wtrans<<<dim3(32, 32), dim3(32, 8), 0, stream>>>(sa_pw, wT_sapw, 1024, 1024);
  wtrans<<<dim3(32, 32), dim3(32, 8), 0, stream>>>(caq_w, wT_caq, 1024, 1024);
  wtrans<<<dim3(64, 32), dim3(32, 8), 0, stream>>>(cakv_w, wT_cakv, 1024, 2048);
  wtrans<<<dim3(32, 32), dim3(32, 8), 0, stream>>>(ca_pw, wT_capw, 1024, 1024);
  wtrans<<<dim3(128, 32), dim3(32, 8), 0, stream>>>(fc_w, wT_fc, 1024, 4096);
  wtrans<<<dim3(32, 128), dim3(32, 8), 0, stream>>>(proj_w, wT_proj, 4096, 1024);
  // qkv: M=8192 N=3072 K=1024
  gemm4<128, 4, 0><<<768, 512, 0, stream>>>(abf, wT_sa, sa_b, nullptr, qkv, 8192, 3072, 1024);
  vtrans<<<dim3(16, 128), 256, 0, stream>>>(qkv, vt1, 1024, 3 * C, 2 * C, H);
  attn4<true><<<dim3(1024), 256, 0, stream>>>(qkv, (long)N * 3 * C, 3 * C,
                                              qkv + C, (long)N * 3 * C, 3 * C,
                                              vt1, ybf, (long)N * C, C, N, H);
  // self-attn proj -> bf16 only
  gemm4<128, 4, 0><<<256, 512, 0, stream>>>(ybf, wT_sapw, sa_pb, nullptr, pbf, 8192, 1024, 1024);
  // LN1: x1bf = LN(pbf)  (x1bf doubles as LN2's residual)
  ln_b<<<8192, 256, 0, stream>>>(pbf, nullptr, ln1_g, ln1_b, nullptr, nullptr, x1bf, C);
  gemm4<128, 4, 0><<<256, 512, 0, stream>>>(x1bf, wT_caq, caq_b, nullptr, q2bf, 8192, 1024, 1024);
  gemm4<128, 4, 0><<<256, 512, 0, stream>>>(encbf, wT_cakv, cakv_b, nullptr, kvbf, 4096, 2048, 1024);
  vtrans<<<dim3(8, 128), 256, 0, stream>>>(kvbf, vt2, 512, 2 * C, C, H);
  attn4<false><<<dim3(1024), 256, 0, stream>>>(q2bf, (long)N * C, C,
                                               kvbf, (long)T * 2 * C, 2 * C,
                                               vt2, y2bf, (long)N * C, C, T, H);
  // cross proj -> bf16 only
  gemm4<128, 4, 0><<<256, 512, 0, stream>>>(y2bf, wT_capw, ca_pb, nullptr, pbf, 8192, 1024, 1024);
  // LN2: x2 = x1bf + pbf -> xres (bf16); LN out -> x1bf (in-place safe, row-local)
  ln_b<<<8192, 256, 0, stream>>>(pbf, x1bf, ln2_g, ln2_b, xres, nullptr, x1bf, C);
  // fc: M=8192 N=4096 K=1024, GELU
  gemm4<256, 2, 1><<<512, 512, 0, stream>>>(x1bf, wT_fc, fc_b, nullptr, hbf, 8192, 4096, 1024);
  // proj: M=8192 N=1024 K=4096 -> bf16 only
  gemm4<128, 4, 0><<<256, 512, 0, stream>>>(hbf, wT_proj, proj_b, nullptr, pbf, 8192, 1024, 4096);
  // LN3: d_out = LN(pbf + xres) (f32)
  ln_b<<<8192, 256, 0, stream>>>(pbf, xres, ln3_g, ln3_b, nullptr, (float*)d_out, nullptr, C);
}